// Round 8
// baseline (35573.117 us; speedup 1.0000x reference)
//
#include <hip/hip_runtime.h>
#include <hip/hip_bf16.h>
#include <stdint.h>

// Problem constants (fixed by the reference): B=64, L=4, H=1024, T=128.
#define NB   64
#define NH   1024
#define NL   4
#define NT   128

using bf16x8 = __attribute__((ext_vector_type(8))) short;  // 8 bf16 in 4 VGPRs
using f32x4  = __attribute__((ext_vector_type(4))) float;

// Split fp32 v into hi+lo bf16 (RNE). v ~= hi + lo with residual ~2^-17 * |v|.
__device__ __forceinline__ void split_bf16(float v, unsigned short& hi, unsigned short& lo) {
    unsigned u = __float_as_uint(v);
    unsigned short h = (unsigned short)((u + 0x7FFFu + ((u >> 16) & 1u)) >> 16);
    float hf = __uint_as_float((unsigned)h << 16);
    float r  = v - hf;
    unsigned ur = __float_as_uint(r);
    unsigned short l = (unsigned short)((ur + 0x7FFFu + ((ur >> 16) & 1u)) >> 16);
    hi = h; lo = l;
}

// A-swizzle for a (64 x 1024) activation: element (m,k) at
// ((k>>5)*4 + (m>>4))*512 + ((m&15) + ((k>>3)&3)*16)*8 + (k&7).   [verified R1-R3]
__device__ __forceinline__ size_t aswz(int m, int k) {
    return ((size_t)((k >> 5) * 4 + (m >> 4)) * 64 + ((m & 15) + ((k >> 3) & 3) * 16)) * 8
           + (k & 7);
}

#define HOFF(p, l) (((size_t)(p) * 4 + (l)) * 65536)

// ---------------------------------------------------------------------------
// prep_w (VERBATIM R3): fp32 W -> swizzled hi/lo bf16 stream.
// Wcat[l][bj][phase 16][tile 4][part 2][512]; tile = 2*kh + (kcl&1),
// phase = kcl>>1. Per-cell-per-block stream = 16 phases x 8 KB, sequential.
// ---------------------------------------------------------------------------
__global__ __launch_bounds__(256)
void prep_w(const float* __restrict__ Wih, const float* __restrict__ Whh,
            unsigned short* __restrict__ Wcat)
{
    int gid = blockIdx.x * 256 + threadIdx.x;      // (l, kc, nt, L)
    int L  = gid & 63;
    int nt = (gid >> 6) & 255;
    int kc = (gid >> 14) & 63;
    int l  = gid >> 20;                            // 0..3
    int np = nt * 16 + (L & 15);                   // n' in [0,4096)
    int g  = np & 3, j = np >> 2;
    int n  = g * 1024 + j;                         // original gate row
    int k0 = kc * 32 + (L >> 4) * 8;               // k in [0,2048)
    const float* src = (k0 < 1024)
        ? (Wih + ((size_t)l * 4096 + n) * 1024 + k0)
        : (Whh + ((size_t)l * 4096 + n) * 1024 + (k0 - 1024));
    float4 s0 = *(const float4*)(src);
    float4 s1 = *(const float4*)(src + 4);
    float sv[8] = {s0.x, s0.y, s0.z, s0.w, s1.x, s1.y, s1.z, s1.w};
    unsigned short hb[8], lb[8];
#pragma unroll
    for (int e = 0; e < 8; ++e) split_bf16(sv[e], hb[e], lb[e]);
    int kh = kc >> 5, kcl = kc & 31;
    int pph = kcl >> 1, tile = 2 * kh + (kcl & 1);
    size_t slotbase = ((size_t)(l * 256 + nt) * 16 + pph) * 4096;
    size_t dsthi = slotbase + (size_t)tile * 1024 + (size_t)L * 8;
    *(ushort4*)&Wcat[dsthi]       = make_ushort4(hb[0], hb[1], hb[2], hb[3]);
    *(ushort4*)&Wcat[dsthi + 4]   = make_ushort4(hb[4], hb[5], hb[6], hb[7]);
    *(ushort4*)&Wcat[dsthi + 512] = make_ushort4(lb[0], lb[1], lb[2], lb[3]);
    *(ushort4*)&Wcat[dsthi + 516] = make_ushort4(lb[4], lb[5], lb[6], lb[7]);
}

// ---------------------------------------------------------------------------
// prep_state (VERBATIM R3)
// ---------------------------------------------------------------------------
__global__ __launch_bounds__(256)
void prep_state(const float* __restrict__ x, const float* __restrict__ h0,
                unsigned short* __restrict__ Xhi, unsigned short* __restrict__ Xlo,
                unsigned short* __restrict__ Hhi, unsigned short* __restrict__ Hlo)
{
    int gid = blockIdx.x * 256 + threadIdx.x;
    if (gid >= 5 * 65536) return;
    int buf = gid >> 16;
    int e = gid & 65535;
    int b = e >> 10, jg = e & 1023;
    float v = (buf == 0) ? x[e] : h0[(size_t)(buf - 1) * 65536 + e];
    size_t idx = aswz(b, jg);
    unsigned short hh, hl; split_bf16(v, hh, hl);
    if (buf == 0) { Xhi[idx] = hh; Xlo[idx] = hl; }
    else {
        Hhi[(size_t)(buf - 1) * 65536 + idx] = hh;
        Hlo[(size_t)(buf - 1) * 65536 + idx] = hl;
    }
}

// ---------------------------------------------------------------------------
// lstm_fused R11: R10 + 2x THREAD-LEVEL PARALLELISM.
// Diagnosis: grid = 256 blocks x 512 thr = 1 block/CU = 2 waves/SIMD
// (OccupancyPercent 24.7 = 8/32 waves). Every latency term (A L2-hits gated
// by the 4-deep ring, B HBM stream, 1-wave epilogue, barrier window) was
// exposed because the SIMD had at most one other wave to switch to. All
// R5-R10 scheduling tweaks moved +-3% for this reason.
// Now: 1024 threads = 16 waves = 4 M-quarters x 2 K-halves x 2 K-subhalves.
// Wave (q, kh, ks) owns pp-sets [ks*8, ks*8+8) of K-half kh: 8 phases/cell
// (same 6-MFMA phase body, 4-deep A-ring, 6-deep B-ring, sched_barrier
// pinning). A/B reads partition exactly (no new duplication). Gs holds 16
// partial tiles; epilogue (wave0) sums 4. Barrier protocol: verbatim R10
// (release-only tree + single pre-arrival buffer_inv; safety argument is
// wave-count-independent). 4 waves/SIMD -> latency trades against TLP.
// ---------------------------------------------------------------------------

#define AISSUE(AV, pp) do {                                                   \
    const unsigned short* _ab = Ah + (size_t)(pp) * 4096 + alane;             \
    const unsigned short* _lb = Al + (size_t)(pp) * 4096 + alane;             \
    AV[0] = *(const bf16x8*)(_ab);                                            \
    AV[1] = *(const bf16x8*)(_lb);                                            \
    AV[2] = *(const bf16x8*)(_ab + 2048);                                     \
    AV[3] = *(const bf16x8*)(_lb + 2048);                                     \
} while (0)

#define BISSUE(BV, pp, stream) do {                                           \
    const unsigned short* _bb = (stream) + (size_t)(pp) * 4096 + blane;       \
    BV[0] = *(const bf16x8*)(_bb);            /* bh0 */                       \
    BV[1] = *(const bf16x8*)(_bb + 512);      /* bl0 */                       \
    BV[2] = *(const bf16x8*)(_bb + 1024);     /* bh1 */                       \
    BV[3] = *(const bf16x8*)(_bb + 1536);     /* bl1 */                       \
} while (0)

// Phase p (0..7): consume A name AC (= av[p&3]) and B name BC (= bw[p&7]);
// p<=3: reload AC with A set kbase+p+4. B: p<=1 -> wsrc set kbase+p+6;
// p>=2 -> NEXT cell's set kbase+p-2, both into BN (= bw[(p+6)&7]).
#define PHASE(p, AC, BC, BN) do {                                             \
    acc0 = __builtin_amdgcn_mfma_f32_16x16x32_bf16(AC[0], BC[0], acc0, 0, 0, 0); \
    acc1 = __builtin_amdgcn_mfma_f32_16x16x32_bf16(AC[1], BC[0], acc1, 0, 0, 0); \
    acc2 = __builtin_amdgcn_mfma_f32_16x16x32_bf16(AC[0], BC[1], acc2, 0, 0, 0); \
    acc0 = __builtin_amdgcn_mfma_f32_16x16x32_bf16(AC[2], BC[2], acc0, 0, 0, 0); \
    acc1 = __builtin_amdgcn_mfma_f32_16x16x32_bf16(AC[3], BC[2], acc1, 0, 0, 0); \
    acc2 = __builtin_amdgcn_mfma_f32_16x16x32_bf16(AC[2], BC[3], acc2, 0, 0, 0); \
    if ((p) <= 3) AISSUE(AC, kbase + (p) + 4);                                \
    if ((p) <= 1) BISSUE(BN, kbase + (p) + 6, wsrc);                          \
    else          BISSUE(BN, kbase + (p) - 2, wnext);                         \
    __builtin_amdgcn_sched_barrier(0);                                        \
} while (0)

__global__ __launch_bounds__(1024, 4)
void lstm_fused(const unsigned short* __restrict__ Wcat,
                const unsigned short* __restrict__ Xhi, const unsigned short* __restrict__ Xlo,
                unsigned short* __restrict__ Hhi, unsigned short* __restrict__ Hlo,
                const float* __restrict__ c0,
                const float* __restrict__ bih, const float* __restrict__ bhh,
                float* __restrict__ out, unsigned* __restrict__ sync)
{
    __shared__ __align__(16) float Gs[5120];                 // 16 tiles x 16 x 20 (pad)
    __shared__ __align__(16) float4 cLd[4][64];              // c state (block-private)
    __shared__ float bcs[64];                                // combined bias

    const int tid = threadIdx.x;
    const int L = tid & 63;
    const int w = tid >> 6;          // 0..15
    const int q = w & 3;             // M-quarter
    const int kh = (w >> 2) & 1;     // K-half: 0 = input, 1 = recurrent
    const int ks = w >> 3;           // K-sub-half within kh
    const int kbase = ks * 8;        // first pp-set of this wave
    const int bj = blockIdx.x;       // n'-tile
    const size_t alane = (size_t)q * 512 + (size_t)L * 8;
    const size_t blane = (size_t)kh * 2048 + (size_t)L * 8;

    // ---- one-time init: bias + c into LDS (wave0 only; wave0 consumes) ----
    if (tid < 64) {
        int li = tid >> 4, i = tid & 15;
        int jj = bj * 4 + (i >> 2), g = i & 3;
        bcs[tid] = bih[li * 4096 + g * 1024 + jj] + bhh[li * 4096 + g * 1024 + jj];
#pragma unroll
        for (int li2 = 0; li2 < 4; ++li2) {
            const float* cs = c0 + (size_t)li2 * 65536 + (size_t)tid * 1024 + bj * 4;
            cLd[li2][tid] = make_float4(cs[0], cs[1], cs[2], cs[3]);
        }
    }

    bf16x8 av0[4], av1[4], av2[4], av3[4];
    bf16x8 bw0[4], bw1[4], bw2[4], bw3[4], bw4[4], bw5[4], bw6[4], bw7[4];
    const unsigned short *Ah, *Al, *wsrc, *wnext;

    // ---- pre-loop prologue: B sets kbase+0..5 of cell 0 into bw0..bw5 ----
    {
        wsrc  = Wcat + (size_t)bj * 65536;            // l=0
        wnext = Wcat + ((size_t)1 * 256 + bj) * 65536;
        BISSUE(bw0, kbase + 0, wsrc); BISSUE(bw1, kbase + 1, wsrc);
        BISSUE(bw2, kbase + 2, wsrc); BISSUE(bw3, kbase + 3, wsrc);
        BISSUE(bw4, kbase + 4, wsrc); BISSUE(bw5, kbase + 5, wsrc);
        __builtin_amdgcn_sched_barrier(0);
    }

#pragma unroll 1
    for (int u = 0; u < NT * NL; ++u) {
        const int t = u >> 2, l = u & 3;
        const int pr = t & 1, pw = pr ^ 1;

        // ---- grid barrier: release-only, pre-arrival inv, tree arrival ----
        if (u) {
            if (tid == 0) {
                // Clean this CU's L1 + XCD L2 of last cell's A lines. No
                // waitcnt attached: the release RMW below orders it, and the
                // flag is only set after all 256 arrivals.
                asm volatile("buffer_inv sc1" ::: "memory");
                unsigned* cg = sync + ((unsigned)bj & 7u) * 16u;   // 64B apart
                unsigned old = __hip_atomic_fetch_add(cg, 1u, __ATOMIC_RELEASE,
                                                      __HIP_MEMORY_SCOPE_AGENT);
                if (old == 32u * (unsigned)u - 1u) {
                    unsigned o2 = __hip_atomic_fetch_add(sync + 128, 1u,
                                                         __ATOMIC_RELEASE,
                                                         __HIP_MEMORY_SCOPE_AGENT);
                    if (o2 == 8u * (unsigned)u - 1u) {
                        __hip_atomic_store(sync + 144, (unsigned)u,
                                           __ATOMIC_RELEASE,
                                           __HIP_MEMORY_SCOPE_AGENT);
                    }
                }
                while (__hip_atomic_load(sync + 144, __ATOMIC_RELAXED,
                                         __HIP_MEMORY_SCOPE_AGENT) < (unsigned)u)
                    __builtin_amdgcn_s_sleep(2);
            }
            asm volatile("s_barrier" ::: "memory");
        }

        // ---- per-cell pointers ----
        {
            const unsigned short *AIh, *AIl;
            if (l == 0) {
                if (t == 0) { AIh = Xhi; AIl = Xlo; }
                else        { AIh = Hhi + HOFF(pr, 3); AIl = Hlo + HOFF(pr, 3); }
            } else          { AIh = Hhi + HOFF(pw, l - 1); AIl = Hlo + HOFF(pw, l - 1); }
            Ah = kh ? (Hhi + HOFF(pr, l)) : AIh;
            Al = kh ? (Hlo + HOFF(pr, l)) : AIl;
            wsrc  = Wcat + ((size_t)l * 256 + bj) * 65536;
            wnext = Wcat + ((size_t)((l + 1) & 3) * 256 + bj) * 65536;
        }

        // ---- A burst: sets kbase+0..3 of this cell ----
        AISSUE(av0, kbase + 0); AISSUE(av1, kbase + 1);
        AISSUE(av2, kbase + 2); AISSUE(av3, kbase + 3);
        __builtin_amdgcn_sched_barrier(0);

        f32x4 acc0 = {0.f, 0.f, 0.f, 0.f};
        f32x4 acc1 = {0.f, 0.f, 0.f, 0.f};
        f32x4 acc2 = {0.f, 0.f, 0.f, 0.f};

        PHASE(0, av0, bw0, bw6);  PHASE(1, av1, bw1, bw7);
        PHASE(2, av2, bw2, bw0);  PHASE(3, av3, bw3, bw1);
        PHASE(4, av0, bw4, bw2);  PHASE(5, av1, bw5, bw3);
        PHASE(6, av2, bw6, bw4);  PHASE(7, av3, bw7, bw5);

        // ---- scatter partials: tile = w; lane holds D[mq*4+r][nl] ----
        {
            f32x4 avv = (acc0 + acc1) + acc2;
            const int mq = L >> 4, nl = L & 15;
            float* gw = &Gs[w * 320 + nl];
#pragma unroll
            for (int r = 0; r < 4; ++r) gw[(mq * 4 + r) * 20] = avv[r];
        }
        asm volatile("s_waitcnt lgkmcnt(0)\n\ts_barrier" ::: "memory");

        // ---- epilogue: wave0, one batch row each, 4 h-dims; sums the 4
        //      (kh, ks) partial tiles of its M-quarter ----
        if (tid < 64) {
            const int bl = tid, qq = bl >> 4, ml = bl & 15;
            float4 cv = cLd[l][bl];
            float ca[4] = {cv.x, cv.y, cv.z, cv.w};
            float hv[4];
            ushort4 h_hi, h_lo;
#pragma unroll
            for (int jl = 0; jl < 4; ++jl) {
                const int base0 = (qq * 16 + ml) * 20 + jl * 4;
                float4 g0 = *(const float4*)&Gs[base0];
                float4 g1 = *(const float4*)&Gs[base0 + 1280];
                float4 g2 = *(const float4*)&Gs[base0 + 2560];
                float4 g3 = *(const float4*)&Gs[base0 + 3840];
                float4 bb = *(const float4*)&bcs[l * 16 + jl * 4];
                float gi = (g0.x + g1.x) + (g2.x + g3.x) + bb.x;
                float gf = (g0.y + g1.y) + (g2.y + g3.y) + bb.y;
                float gg = (g0.z + g1.z) + (g2.z + g3.z) + bb.z;
                float go = (g0.w + g1.w) + (g2.w + g3.w) + bb.w;
                float si = 1.f / (1.f + __expf(-gi));
                float sf = 1.f / (1.f + __expf(-gf));
                float so = 1.f / (1.f + __expf(-go));
                float tg = 1.f - 2.f / (__expf(2.f * gg) + 1.f);
                float cn = sf * ca[jl] + si * tg;
                ca[jl] = cn;
                float tc = 1.f - 2.f / (__expf(2.f * cn) + 1.f);
                hv[jl] = so * tc;
                unsigned short hh, hl; split_bf16(hv[jl], hh, hl);
                ((unsigned short*)&h_hi)[jl] = hh;
                ((unsigned short*)&h_lo)[jl] = hl;
            }
            cLd[l][bl] = make_float4(ca[0], ca[1], ca[2], ca[3]);
            size_t hidx = aswz(bl, bj * 4);
            union { ushort4 v; unsigned long long u; } ch, cl2;
            ch.v = h_hi; cl2.v = h_lo;
            __hip_atomic_store((unsigned long long*)(Hhi + HOFF(pw, l) + hidx), ch.u,
                               __ATOMIC_RELAXED, __HIP_MEMORY_SCOPE_AGENT);
            __hip_atomic_store((unsigned long long*)(Hlo + HOFF(pw, l) + hidx), cl2.u,
                               __ATOMIC_RELAXED, __HIP_MEMORY_SCOPE_AGENT);
            if (l == 3) {
                // write-through (agent atomic) so a buffer_inv can never drop
                // a dirty out line from L2.
                union { float4 f; unsigned long long uu[2]; } ov;
                ov.f = make_float4(hv[0], hv[1], hv[2], hv[3]);
                unsigned long long* op = (unsigned long long*)
                    &out[(size_t)bl * (NT * NH) + (size_t)t * NH + bj * 4];
                __hip_atomic_store(op,     ov.uu[0], __ATOMIC_RELAXED,
                                   __HIP_MEMORY_SCOPE_AGENT);
                __hip_atomic_store(op + 1, ov.uu[1], __ATOMIC_RELAXED,
                                   __HIP_MEMORY_SCOPE_AGENT);
            }
        }
    }
}

// ---------------------------------------------------------------------------
extern "C" void kernel_launch(void* const* d_in, const int* in_sizes, int n_in,
                              void* d_out, int out_size, void* d_ws, size_t ws_size,
                              hipStream_t stream)
{
    const float* x   = (const float*)d_in[0];
    const float* h0  = (const float*)d_in[1];
    const float* c0  = (const float*)d_in[2];
    const float* Wih = (const float*)d_in[3];
    const float* Whh = (const float*)d_in[4];
    const float* bih = (const float*)d_in[5];
    const float* bhh = (const float*)d_in[6];
    float* out = (float*)d_out;

    char* ws = (char*)d_ws;
    size_t off = 0;
    auto alloc = [&](size_t bytes) -> char* {
        char* p = ws + off; off += (bytes + 255) & ~(size_t)255; return p;
    };
    unsigned short* Wcat = (unsigned short*)alloc((size_t)4 * 256 * 65536 * 2);  // 128 MiB
    unsigned short* Xhi  = (unsigned short*)alloc(65536 * 2);
    unsigned short* Xlo  = (unsigned short*)alloc(65536 * 2);
    unsigned short* Hhi  = (unsigned short*)alloc((size_t)2 * 4 * 65536 * 2);
    unsigned short* Hlo  = (unsigned short*)alloc((size_t)2 * 4 * 65536 * 2);
    unsigned*       sync = (unsigned*)alloc(1024);

    hipMemsetAsync(sync, 0, 1024, stream);
    prep_w<<<16384, 256, 0, stream>>>(Wih, Whh, Wcat);
    prep_state<<<1280, 256, 0, stream>>>(x, h0, Xhi, Xlo, Hhi, Hlo);

    void* kargs[] = { (void*)&Wcat, (void*)&Xhi, (void*)&Xlo, (void*)&Hhi, (void*)&Hlo,
                      (void*)&c0, (void*)&bih, (void*)&bhh, (void*)&out, (void*)&sync };
    hipLaunchCooperativeKernel((void*)lstm_fused, dim3(256), dim3(1024), kargs, 0, stream);

    (void)in_sizes; (void)n_in; (void)out_size; (void)ws_size;
}

// Round 9
// 7887.640 us; speedup vs baseline: 4.5100x; 4.5100x over previous
//
#include <hip/hip_runtime.h>
#include <hip/hip_bf16.h>
#include <stdint.h>

// Problem constants (fixed by the reference): B=64, L=4, H=1024, T=128.
#define NB   64
#define NH   1024
#define NL   4
#define NT   128

using bf16x8 = __attribute__((ext_vector_type(8))) short;  // 8 bf16 in 4 VGPRs
using f32x4  = __attribute__((ext_vector_type(4))) float;

// Split fp32 v into hi+lo bf16 (RNE). v ~= hi + lo with residual ~2^-17 * |v|.
__device__ __forceinline__ void split_bf16(float v, unsigned short& hi, unsigned short& lo) {
    unsigned u = __float_as_uint(v);
    unsigned short h = (unsigned short)((u + 0x7FFFu + ((u >> 16) & 1u)) >> 16);
    float hf = __uint_as_float((unsigned)h << 16);
    float r  = v - hf;
    unsigned ur = __float_as_uint(r);
    unsigned short l = (unsigned short)((ur + 0x7FFFu + ((ur >> 16) & 1u)) >> 16);
    hi = h; lo = l;
}

// A-swizzle for a (64 x 1024) activation: element (m,k) at
// ((k>>5)*4 + (m>>4))*512 + ((m&15) + ((k>>3)&3)*16)*8 + (k&7).   [verified R1-R3]
__device__ __forceinline__ size_t aswz(int m, int k) {
    return ((size_t)((k >> 5) * 4 + (m >> 4)) * 64 + ((m & 15) + ((k >> 3) & 3) * 16)) * 8
           + (k & 7);
}

#define HOFF(p, l) (((size_t)(p) * 4 + (l)) * 65536)

// ---------------------------------------------------------------------------
// prep_w (VERBATIM R3): fp32 W -> swizzled hi/lo bf16 stream.
// Wcat[l][bj][phase 16][tile 4][part 2][512]; tile = 2*kh + (kcl&1),
// phase = kcl>>1. Per-cell-per-block stream = 16 phases x 8 KB, sequential.
// ---------------------------------------------------------------------------
__global__ __launch_bounds__(256)
void prep_w(const float* __restrict__ Wih, const float* __restrict__ Whh,
            unsigned short* __restrict__ Wcat)
{
    int gid = blockIdx.x * 256 + threadIdx.x;      // (l, kc, nt, L)
    int L  = gid & 63;
    int nt = (gid >> 6) & 255;
    int kc = (gid >> 14) & 63;
    int l  = gid >> 20;                            // 0..3
    int np = nt * 16 + (L & 15);                   // n' in [0,4096)
    int g  = np & 3, j = np >> 2;
    int n  = g * 1024 + j;                         // original gate row
    int k0 = kc * 32 + (L >> 4) * 8;               // k in [0,2048)
    const float* src = (k0 < 1024)
        ? (Wih + ((size_t)l * 4096 + n) * 1024 + k0)
        : (Whh + ((size_t)l * 4096 + n) * 1024 + (k0 - 1024));
    float4 s0 = *(const float4*)(src);
    float4 s1 = *(const float4*)(src + 4);
    float sv[8] = {s0.x, s0.y, s0.z, s0.w, s1.x, s1.y, s1.z, s1.w};
    unsigned short hb[8], lb[8];
#pragma unroll
    for (int e = 0; e < 8; ++e) split_bf16(sv[e], hb[e], lb[e]);
    int kh = kc >> 5, kcl = kc & 31;
    int pph = kcl >> 1, tile = 2 * kh + (kcl & 1);
    size_t slotbase = ((size_t)(l * 256 + nt) * 16 + pph) * 4096;
    size_t dsthi = slotbase + (size_t)tile * 1024 + (size_t)L * 8;
    *(ushort4*)&Wcat[dsthi]       = make_ushort4(hb[0], hb[1], hb[2], hb[3]);
    *(ushort4*)&Wcat[dsthi + 4]   = make_ushort4(hb[4], hb[5], hb[6], hb[7]);
    *(ushort4*)&Wcat[dsthi + 512] = make_ushort4(lb[0], lb[1], lb[2], lb[3]);
    *(ushort4*)&Wcat[dsthi + 516] = make_ushort4(lb[4], lb[5], lb[6], lb[7]);
}

// ---------------------------------------------------------------------------
// prep_state (VERBATIM R3)
// ---------------------------------------------------------------------------
__global__ __launch_bounds__(256)
void prep_state(const float* __restrict__ x, const float* __restrict__ h0,
                unsigned short* __restrict__ Xhi, unsigned short* __restrict__ Xlo,
                unsigned short* __restrict__ Hhi, unsigned short* __restrict__ Hlo)
{
    int gid = blockIdx.x * 256 + threadIdx.x;
    if (gid >= 5 * 65536) return;
    int buf = gid >> 16;
    int e = gid & 65535;
    int b = e >> 10, jg = e & 1023;
    float v = (buf == 0) ? x[e] : h0[(size_t)(buf - 1) * 65536 + e];
    size_t idx = aswz(b, jg);
    unsigned short hh, hl; split_bf16(v, hh, hl);
    if (buf == 0) { Xhi[idx] = hh; Xlo[idx] = hl; }
    else {
        Hhi[(size_t)(buf - 1) * 65536 + idx] = hh;
        Hlo[(size_t)(buf - 1) * 65536 + idx] = hl;
    }
}

// ---------------------------------------------------------------------------
// lstm_fused R12: R10 (7861 us, best) + 8-DEEP SAME-NAME B-RING.
// R11 lesson: launch_bounds(1024,4) capped VGPR at 128 -> rings spilled to
// scratch (WRITE 0.4->59 GB, 100 GB total HBM) -> 4.5x regression. BUT its
// spill traffic sustained 2.84 TB/s, proving the fabric has >2x headroom
// over R10's 1.28 TB/s: R10 is CONCURRENCY-limited (Little's law), and at
// 2 waves/SIMD the VGPR cap is 256 with only 112 used.
// Change (one): B-ring 6-deep/8-name -> 8-deep/8-name with same-name
// reload: phase p consumes bw[p&7], then immediately reissues set p+8 into
// bw[p&7] (p<=7: wsrc set p+8; p>=8: wnext set p-8). All 8 names are
// permanently in flight (128 VGPR B + 64 A + ~30 misc ~= 220 < 256).
// Prologue loads sets 0..7. Cell-start invariant preserved: at each cell's
// phase 0, bw0..bw7 hold that cell's sets 0..7. sched_barrier(0) pinning,
// A-ring, barrier protocol (release-only tree + single pre-arrival inv),
// scatter, epilogue: verbatim R10.
// ---------------------------------------------------------------------------

#define AISSUE(AV, pp) do {                                                   \
    const unsigned short* _ab = Ah + (size_t)(pp) * 4096 + alane;             \
    const unsigned short* _lb = Al + (size_t)(pp) * 4096 + alane;             \
    AV[0] = *(const bf16x8*)(_ab);                                            \
    AV[1] = *(const bf16x8*)(_lb);                                            \
    AV[2] = *(const bf16x8*)(_ab + 2048);                                     \
    AV[3] = *(const bf16x8*)(_lb + 2048);                                     \
} while (0)

#define BISSUE(BV, pp, stream) do {                                           \
    const unsigned short* _bb = (stream) + (size_t)(pp) * 4096 + blane;       \
    BV[0] = *(const bf16x8*)(_bb);            /* bh0 */                       \
    BV[1] = *(const bf16x8*)(_bb + 512);      /* bl0 */                       \
    BV[2] = *(const bf16x8*)(_bb + 1024);     /* bh1 */                       \
    BV[3] = *(const bf16x8*)(_bb + 1536);     /* bl1 */                       \
} while (0)

// Phase p: consume A name AC (= av[p&3]) and B name BC (= bw[p&7]);
// reload AC with A set p+4 (p<=11); reload BC with B set p+8
// (p<=7: this cell via wsrc; p>=8: next cell via wnext).
#define PHASE(p, AC, BC) do {                                                 \
    acc0 = __builtin_amdgcn_mfma_f32_16x16x32_bf16(AC[0], BC[0], acc0, 0, 0, 0); \
    acc1 = __builtin_amdgcn_mfma_f32_16x16x32_bf16(AC[1], BC[0], acc1, 0, 0, 0); \
    acc2 = __builtin_amdgcn_mfma_f32_16x16x32_bf16(AC[0], BC[1], acc2, 0, 0, 0); \
    acc0 = __builtin_amdgcn_mfma_f32_16x16x32_bf16(AC[2], BC[2], acc0, 0, 0, 0); \
    acc1 = __builtin_amdgcn_mfma_f32_16x16x32_bf16(AC[3], BC[2], acc1, 0, 0, 0); \
    acc2 = __builtin_amdgcn_mfma_f32_16x16x32_bf16(AC[2], BC[3], acc2, 0, 0, 0); \
    if ((p) <= 11) AISSUE(AC, (p) + 4);                                       \
    if ((p) <= 7)  BISSUE(BC, (p) + 8, wsrc);                                 \
    else           BISSUE(BC, (p) - 8, wnext);                                \
    __builtin_amdgcn_sched_barrier(0);                                        \
} while (0)

__global__ __launch_bounds__(512, 2)
void lstm_fused(const unsigned short* __restrict__ Wcat,
                const unsigned short* __restrict__ Xhi, const unsigned short* __restrict__ Xlo,
                unsigned short* __restrict__ Hhi, unsigned short* __restrict__ Hlo,
                const float* __restrict__ c0,
                const float* __restrict__ bih, const float* __restrict__ bhh,
                float* __restrict__ out, unsigned* __restrict__ sync)
{
    __shared__ __align__(16) float Gs[2560];                 // 8 tiles x 16 x 20 (pad)
    __shared__ __align__(16) float4 cLd[4][64];              // c state (block-private)
    __shared__ float bcs[64];                                // combined bias

    const int tid = threadIdx.x;
    const int L = tid & 63;
    const int w = tid >> 6;          // 0..7
    const int q = w & 3;             // M-quarter
    const int kh = w >> 2;           // K-half: 0 = input, 1 = recurrent
    const int bj = blockIdx.x;       // n'-tile
    const size_t alane = (size_t)q * 512 + (size_t)L * 8;
    const size_t blane = (size_t)kh * 2048 + (size_t)L * 8;

    // ---- one-time init: bias + c into LDS (wave0 only; wave0 consumes) ----
    if (tid < 64) {
        int li = tid >> 4, i = tid & 15;
        int jj = bj * 4 + (i >> 2), g = i & 3;
        bcs[tid] = bih[li * 4096 + g * 1024 + jj] + bhh[li * 4096 + g * 1024 + jj];
#pragma unroll
        for (int li2 = 0; li2 < 4; ++li2) {
            const float* cs = c0 + (size_t)li2 * 65536 + (size_t)tid * 1024 + bj * 4;
            cLd[li2][tid] = make_float4(cs[0], cs[1], cs[2], cs[3]);
        }
    }

    bf16x8 av0[4], av1[4], av2[4], av3[4];
    bf16x8 bw0[4], bw1[4], bw2[4], bw3[4], bw4[4], bw5[4], bw6[4], bw7[4];
    const unsigned short *Ah, *Al, *wsrc, *wnext;

    // ---- pre-loop prologue: B sets 0..7 of cell 0 into bw0..bw7 ----
    {
        wsrc  = Wcat + (size_t)bj * 65536;            // l=0
        wnext = Wcat + ((size_t)1 * 256 + bj) * 65536;
        BISSUE(bw0, 0, wsrc); BISSUE(bw1, 1, wsrc); BISSUE(bw2, 2, wsrc);
        BISSUE(bw3, 3, wsrc); BISSUE(bw4, 4, wsrc); BISSUE(bw5, 5, wsrc);
        BISSUE(bw6, 6, wsrc); BISSUE(bw7, 7, wsrc);
        __builtin_amdgcn_sched_barrier(0);
    }

#pragma unroll 1
    for (int u = 0; u < NT * NL; ++u) {
        const int t = u >> 2, l = u & 3;
        const int pr = t & 1, pw = pr ^ 1;

        // ---- grid barrier: release-only, pre-arrival inv, tree arrival ----
        if (u) {
            if (tid == 0) {
                // Clean this CU's L1 + XCD L2 of last cell's A lines. No
                // waitcnt attached: the release RMW below orders it, and the
                // flag is only set after all 256 arrivals.
                asm volatile("buffer_inv sc1" ::: "memory");
                unsigned* cg = sync + ((unsigned)bj & 7u) * 16u;   // 64B apart
                unsigned old = __hip_atomic_fetch_add(cg, 1u, __ATOMIC_RELEASE,
                                                      __HIP_MEMORY_SCOPE_AGENT);
                if (old == 32u * (unsigned)u - 1u) {
                    unsigned o2 = __hip_atomic_fetch_add(sync + 128, 1u,
                                                         __ATOMIC_RELEASE,
                                                         __HIP_MEMORY_SCOPE_AGENT);
                    if (o2 == 8u * (unsigned)u - 1u) {
                        __hip_atomic_store(sync + 144, (unsigned)u,
                                           __ATOMIC_RELEASE,
                                           __HIP_MEMORY_SCOPE_AGENT);
                    }
                }
                while (__hip_atomic_load(sync + 144, __ATOMIC_RELAXED,
                                         __HIP_MEMORY_SCOPE_AGENT) < (unsigned)u)
                    __builtin_amdgcn_s_sleep(2);
            }
            asm volatile("s_barrier" ::: "memory");
        }

        // ---- per-cell pointers ----
        {
            const unsigned short *AIh, *AIl;
            if (l == 0) {
                if (t == 0) { AIh = Xhi; AIl = Xlo; }
                else        { AIh = Hhi + HOFF(pr, 3); AIl = Hlo + HOFF(pr, 3); }
            } else          { AIh = Hhi + HOFF(pw, l - 1); AIl = Hlo + HOFF(pw, l - 1); }
            Ah = kh ? (Hhi + HOFF(pr, l)) : AIh;
            Al = kh ? (Hlo + HOFF(pr, l)) : AIl;
            wsrc  = Wcat + ((size_t)l * 256 + bj) * 65536;
            wnext = Wcat + ((size_t)((l + 1) & 3) * 256 + bj) * 65536;
        }

        // ---- A burst: sets 0..3 of this cell (h just became visible) ----
        AISSUE(av0, 0); AISSUE(av1, 1); AISSUE(av2, 2); AISSUE(av3, 3);
        __builtin_amdgcn_sched_barrier(0);

        f32x4 acc0 = {0.f, 0.f, 0.f, 0.f};
        f32x4 acc1 = {0.f, 0.f, 0.f, 0.f};
        f32x4 acc2 = {0.f, 0.f, 0.f, 0.f};

        PHASE( 0, av0, bw0);  PHASE( 1, av1, bw1);
        PHASE( 2, av2, bw2);  PHASE( 3, av3, bw3);
        PHASE( 4, av0, bw4);  PHASE( 5, av1, bw5);
        PHASE( 6, av2, bw6);  PHASE( 7, av3, bw7);
        PHASE( 8, av0, bw0);  PHASE( 9, av1, bw1);
        PHASE(10, av2, bw2);  PHASE(11, av3, bw3);
        PHASE(12, av0, bw4);  PHASE(13, av1, bw5);
        PHASE(14, av2, bw6);  PHASE(15, av3, bw7);

        // ---- scatter partials: tile = kh*4+q; lane holds D[mq*4+r][nl] ----
        {
            f32x4 avv = (acc0 + acc1) + acc2;
            const int mq = L >> 4, nl = L & 15;
            float* gw = &Gs[(kh * 4 + q) * 320 + nl];
#pragma unroll
            for (int r = 0; r < 4; ++r) gw[(mq * 4 + r) * 20] = avv[r];
        }
        asm volatile("s_waitcnt lgkmcnt(0)\n\ts_barrier" ::: "memory");

        // ---- epilogue: wave0, one batch row each, 4 h-dims (R3-verified) ----
        if (tid < 64) {
            const int bl = tid, qq = bl >> 4, ml = bl & 15;
            float4 cv = cLd[l][bl];
            float ca[4] = {cv.x, cv.y, cv.z, cv.w};
            float hv[4];
            ushort4 h_hi, h_lo;
#pragma unroll
            for (int jl = 0; jl < 4; ++jl) {
                const int base0 = (qq * 16 + ml) * 20 + jl * 4;
                float4 g0 = *(const float4*)&Gs[base0];
                float4 g1 = *(const float4*)&Gs[base0 + 1280];
                float4 bb = *(const float4*)&bcs[l * 16 + jl * 4];
                float gi = g0.x + g1.x + bb.x;
                float gf = g0.y + g1.y + bb.y;
                float gg = g0.z + g1.z + bb.z;
                float go = g0.w + g1.w + bb.w;
                float si = 1.f / (1.f + __expf(-gi));
                float sf = 1.f / (1.f + __expf(-gf));
                float so = 1.f / (1.f + __expf(-go));
                float tg = 1.f - 2.f / (__expf(2.f * gg) + 1.f);
                float cn = sf * ca[jl] + si * tg;
                ca[jl] = cn;
                float tc = 1.f - 2.f / (__expf(2.f * cn) + 1.f);
                hv[jl] = so * tc;
                unsigned short hh, hl; split_bf16(hv[jl], hh, hl);
                ((unsigned short*)&h_hi)[jl] = hh;
                ((unsigned short*)&h_lo)[jl] = hl;
            }
            cLd[l][bl] = make_float4(ca[0], ca[1], ca[2], ca[3]);
            size_t hidx = aswz(bl, bj * 4);
            union { ushort4 v; unsigned long long u; } ch, cl2;
            ch.v = h_hi; cl2.v = h_lo;
            __hip_atomic_store((unsigned long long*)(Hhi + HOFF(pw, l) + hidx), ch.u,
                               __ATOMIC_RELAXED, __HIP_MEMORY_SCOPE_AGENT);
            __hip_atomic_store((unsigned long long*)(Hlo + HOFF(pw, l) + hidx), cl2.u,
                               __ATOMIC_RELAXED, __HIP_MEMORY_SCOPE_AGENT);
            if (l == 3) {
                // write-through (agent atomic) so a buffer_inv can never drop
                // a dirty out line from L2.
                union { float4 f; unsigned long long uu[2]; } ov;
                ov.f = make_float4(hv[0], hv[1], hv[2], hv[3]);
                unsigned long long* op = (unsigned long long*)
                    &out[(size_t)bl * (NT * NH) + (size_t)t * NH + bj * 4];
                __hip_atomic_store(op,     ov.uu[0], __ATOMIC_RELAXED,
                                   __HIP_MEMORY_SCOPE_AGENT);
                __hip_atomic_store(op + 1, ov.uu[1], __ATOMIC_RELAXED,
                                   __HIP_MEMORY_SCOPE_AGENT);
            }
        }
    }
}

// ---------------------------------------------------------------------------
extern "C" void kernel_launch(void* const* d_in, const int* in_sizes, int n_in,
                              void* d_out, int out_size, void* d_ws, size_t ws_size,
                              hipStream_t stream)
{
    const float* x   = (const float*)d_in[0];
    const float* h0  = (const float*)d_in[1];
    const float* c0  = (const float*)d_in[2];
    const float* Wih = (const float*)d_in[3];
    const float* Whh = (const float*)d_in[4];
    const float* bih = (const float*)d_in[5];
    const float* bhh = (const float*)d_in[6];
    float* out = (float*)d_out;

    char* ws = (char*)d_ws;
    size_t off = 0;
    auto alloc = [&](size_t bytes) -> char* {
        char* p = ws + off; off += (bytes + 255) & ~(size_t)255; return p;
    };
    unsigned short* Wcat = (unsigned short*)alloc((size_t)4 * 256 * 65536 * 2);  // 128 MiB
    unsigned short* Xhi  = (unsigned short*)alloc(65536 * 2);
    unsigned short* Xlo  = (unsigned short*)alloc(65536 * 2);
    unsigned short* Hhi  = (unsigned short*)alloc((size_t)2 * 4 * 65536 * 2);
    unsigned short* Hlo  = (unsigned short*)alloc((size_t)2 * 4 * 65536 * 2);
    unsigned*       sync = (unsigned*)alloc(1024);

    hipMemsetAsync(sync, 0, 1024, stream);
    prep_w<<<16384, 256, 0, stream>>>(Wih, Whh, Wcat);
    prep_state<<<1280, 256, 0, stream>>>(x, h0, Xhi, Xlo, Hhi, Hlo);

    void* kargs[] = { (void*)&Wcat, (void*)&Xhi, (void*)&Xlo, (void*)&Hhi, (void*)&Hlo,
                      (void*)&c0, (void*)&bih, (void*)&bhh, (void*)&out, (void*)&sync };
    hipLaunchCooperativeKernel((void*)lstm_fused, dim3(256), dim3(512), kargs, 0, stream);

    (void)in_sizes; (void)n_in; (void)out_size; (void)ws_size;
}

// Round 10
// 7253.601 us; speedup vs baseline: 4.9042x; 1.0874x over previous
//
#include <hip/hip_runtime.h>
#include <hip/hip_bf16.h>
#include <stdint.h>

// Problem constants (fixed by the reference): B=64, L=4, H=1024, T=128.
#define NB   64
#define NH   1024
#define NL   4
#define NT   128

using bf16x8 = __attribute__((ext_vector_type(8))) short;  // 8 bf16 in 4 VGPRs
using f32x4  = __attribute__((ext_vector_type(4))) float;

// Split fp32 v into hi+lo bf16 (RNE). v ~= hi + lo with residual ~2^-17 * |v|.
__device__ __forceinline__ void split_bf16(float v, unsigned short& hi, unsigned short& lo) {
    unsigned u = __float_as_uint(v);
    unsigned short h = (unsigned short)((u + 0x7FFFu + ((u >> 16) & 1u)) >> 16);
    float hf = __uint_as_float((unsigned)h << 16);
    float r  = v - hf;
    unsigned ur = __float_as_uint(r);
    unsigned short l = (unsigned short)((ur + 0x7FFFu + ((ur >> 16) & 1u)) >> 16);
    hi = h; lo = l;
}

// A-swizzle for a (64 x 1024) activation: element (m,k) at
// ((k>>5)*4 + (m>>4))*512 + ((m&15) + ((k>>3)&3)*16)*8 + (k&7).   [verified R1-R3]
__device__ __forceinline__ size_t aswz(int m, int k) {
    return ((size_t)((k >> 5) * 4 + (m >> 4)) * 64 + ((m & 15) + ((k >> 3) & 3) * 16)) * 8
           + (k & 7);
}

#define HOFF(p, l) (((size_t)(p) * 4 + (l)) * 65536)

// ---------------------------------------------------------------------------
// prep_w (VERBATIM R3): fp32 W -> swizzled hi/lo bf16 stream.
// Wcat[l][bj][phase 16][tile 4][part 2][512]; tile = 2*kh + (kcl&1),
// phase = kcl>>1. Per-cell-per-block stream = 16 phases x 8 KB, sequential.
// ---------------------------------------------------------------------------
__global__ __launch_bounds__(256)
void prep_w(const float* __restrict__ Wih, const float* __restrict__ Whh,
            unsigned short* __restrict__ Wcat)
{
    int gid = blockIdx.x * 256 + threadIdx.x;      // (l, kc, nt, L)
    int L  = gid & 63;
    int nt = (gid >> 6) & 255;
    int kc = (gid >> 14) & 63;
    int l  = gid >> 20;                            // 0..3
    int np = nt * 16 + (L & 15);                   // n' in [0,4096)
    int g  = np & 3, j = np >> 2;
    int n  = g * 1024 + j;                         // original gate row
    int k0 = kc * 32 + (L >> 4) * 8;               // k in [0,2048)
    const float* src = (k0 < 1024)
        ? (Wih + ((size_t)l * 4096 + n) * 1024 + k0)
        : (Whh + ((size_t)l * 4096 + n) * 1024 + (k0 - 1024));
    float4 s0 = *(const float4*)(src);
    float4 s1 = *(const float4*)(src + 4);
    float sv[8] = {s0.x, s0.y, s0.z, s0.w, s1.x, s1.y, s1.z, s1.w};
    unsigned short hb[8], lb[8];
#pragma unroll
    for (int e = 0; e < 8; ++e) split_bf16(sv[e], hb[e], lb[e]);
    int kh = kc >> 5, kcl = kc & 31;
    int pph = kcl >> 1, tile = 2 * kh + (kcl & 1);
    size_t slotbase = ((size_t)(l * 256 + nt) * 16 + pph) * 4096;
    size_t dsthi = slotbase + (size_t)tile * 1024 + (size_t)L * 8;
    *(ushort4*)&Wcat[dsthi]       = make_ushort4(hb[0], hb[1], hb[2], hb[3]);
    *(ushort4*)&Wcat[dsthi + 4]   = make_ushort4(hb[4], hb[5], hb[6], hb[7]);
    *(ushort4*)&Wcat[dsthi + 512] = make_ushort4(lb[0], lb[1], lb[2], lb[3]);
    *(ushort4*)&Wcat[dsthi + 516] = make_ushort4(lb[4], lb[5], lb[6], lb[7]);
}

// ---------------------------------------------------------------------------
// prep_state (VERBATIM R3)
// ---------------------------------------------------------------------------
__global__ __launch_bounds__(256)
void prep_state(const float* __restrict__ x, const float* __restrict__ h0,
                unsigned short* __restrict__ Xhi, unsigned short* __restrict__ Xlo,
                unsigned short* __restrict__ Hhi, unsigned short* __restrict__ Hlo)
{
    int gid = blockIdx.x * 256 + threadIdx.x;
    if (gid >= 5 * 65536) return;
    int buf = gid >> 16;
    int e = gid & 65535;
    int b = e >> 10, jg = e & 1023;
    float v = (buf == 0) ? x[e] : h0[(size_t)(buf - 1) * 65536 + e];
    size_t idx = aswz(b, jg);
    unsigned short hh, hl; split_bf16(v, hh, hl);
    if (buf == 0) { Xhi[idx] = hh; Xlo[idx] = hl; }
    else {
        Hhi[(size_t)(buf - 1) * 65536 + idx] = hh;
        Hlo[(size_t)(buf - 1) * 65536 + idx] = hl;
    }
}

// ---------------------------------------------------------------------------
// lstm_fused R13: R12 + INV ONCE PER TIMESTEP (u%4==0) instead of per cell.
// Why safe (same assumptions as per-cell inv):
//   Reads at cell u touch h written at u-1 / u-4. Within one timestep window
//   [4t,4t+4): each h buffer is either written in-window with every in-window
//   cached read occurring AFTER the write (input chain h[pw][l-1], read at
//   cell 4t+l), or not written in-window at all (recurrent h[pr][l], written
//   in window t-1; its in-window-(t-1) cached reads also all post-write).
//   Stale lines from >=1 window ago are wiped by the window-start inv. So
//   the set of possible stale-hit windows is IDENTICAL to per-cell inv.
// Why faster: blocks arrive at barriers staggered, so per-cell invs wiped
// the XCD L2 ~32 times per cell at random points, destroying sibling
// blocks' freshly-filled A lines mid-cell -> the 131 MB/cell A-broadcast
// was LLC-served. Now 3 of 4 cells run with an intact L2: the 32 blocks
// per XCD share one A fill (512 KB from LLC instead of 32x512 KB).
// Everything else verbatim R12 (8-name B-ring with same-name reload,
// 4-deep A-ring, sched_barrier(0) pinning, release-only tree barrier,
// agent-scope write-through h/out stores).
// ---------------------------------------------------------------------------

#define AISSUE(AV, pp) do {                                                   \
    const unsigned short* _ab = Ah + (size_t)(pp) * 4096 + alane;             \
    const unsigned short* _lb = Al + (size_t)(pp) * 4096 + alane;             \
    AV[0] = *(const bf16x8*)(_ab);                                            \
    AV[1] = *(const bf16x8*)(_lb);                                            \
    AV[2] = *(const bf16x8*)(_ab + 2048);                                     \
    AV[3] = *(const bf16x8*)(_lb + 2048);                                     \
} while (0)

#define BISSUE(BV, pp, stream) do {                                           \
    const unsigned short* _bb = (stream) + (size_t)(pp) * 4096 + blane;       \
    BV[0] = *(const bf16x8*)(_bb);            /* bh0 */                       \
    BV[1] = *(const bf16x8*)(_bb + 512);      /* bl0 */                       \
    BV[2] = *(const bf16x8*)(_bb + 1024);     /* bh1 */                       \
    BV[3] = *(const bf16x8*)(_bb + 1536);     /* bl1 */                       \
} while (0)

// Phase p: consume A name AC (= av[p&3]) and B name BC (= bw[p&7]);
// reload AC with A set p+4 (p<=11); reload BC with B set p+8
// (p<=7: this cell via wsrc; p>=8: next cell via wnext).
#define PHASE(p, AC, BC) do {                                                 \
    acc0 = __builtin_amdgcn_mfma_f32_16x16x32_bf16(AC[0], BC[0], acc0, 0, 0, 0); \
    acc1 = __builtin_amdgcn_mfma_f32_16x16x32_bf16(AC[1], BC[0], acc1, 0, 0, 0); \
    acc2 = __builtin_amdgcn_mfma_f32_16x16x32_bf16(AC[0], BC[1], acc2, 0, 0, 0); \
    acc0 = __builtin_amdgcn_mfma_f32_16x16x32_bf16(AC[2], BC[2], acc0, 0, 0, 0); \
    acc1 = __builtin_amdgcn_mfma_f32_16x16x32_bf16(AC[3], BC[2], acc1, 0, 0, 0); \
    acc2 = __builtin_amdgcn_mfma_f32_16x16x32_bf16(AC[2], BC[3], acc2, 0, 0, 0); \
    if ((p) <= 11) AISSUE(AC, (p) + 4);                                       \
    if ((p) <= 7)  BISSUE(BC, (p) + 8, wsrc);                                 \
    else           BISSUE(BC, (p) - 8, wnext);                                \
    __builtin_amdgcn_sched_barrier(0);                                        \
} while (0)

__global__ __launch_bounds__(512, 2)
void lstm_fused(const unsigned short* __restrict__ Wcat,
                const unsigned short* __restrict__ Xhi, const unsigned short* __restrict__ Xlo,
                unsigned short* __restrict__ Hhi, unsigned short* __restrict__ Hlo,
                const float* __restrict__ c0,
                const float* __restrict__ bih, const float* __restrict__ bhh,
                float* __restrict__ out, unsigned* __restrict__ sync)
{
    __shared__ __align__(16) float Gs[2560];                 // 8 tiles x 16 x 20 (pad)
    __shared__ __align__(16) float4 cLd[4][64];              // c state (block-private)
    __shared__ float bcs[64];                                // combined bias

    const int tid = threadIdx.x;
    const int L = tid & 63;
    const int w = tid >> 6;          // 0..7
    const int q = w & 3;             // M-quarter
    const int kh = w >> 2;           // K-half: 0 = input, 1 = recurrent
    const int bj = blockIdx.x;       // n'-tile
    const size_t alane = (size_t)q * 512 + (size_t)L * 8;
    const size_t blane = (size_t)kh * 2048 + (size_t)L * 8;

    // ---- one-time init: bias + c into LDS (wave0 only; wave0 consumes) ----
    if (tid < 64) {
        int li = tid >> 4, i = tid & 15;
        int jj = bj * 4 + (i >> 2), g = i & 3;
        bcs[tid] = bih[li * 4096 + g * 1024 + jj] + bhh[li * 4096 + g * 1024 + jj];
#pragma unroll
        for (int li2 = 0; li2 < 4; ++li2) {
            const float* cs = c0 + (size_t)li2 * 65536 + (size_t)tid * 1024 + bj * 4;
            cLd[li2][tid] = make_float4(cs[0], cs[1], cs[2], cs[3]);
        }
    }

    bf16x8 av0[4], av1[4], av2[4], av3[4];
    bf16x8 bw0[4], bw1[4], bw2[4], bw3[4], bw4[4], bw5[4], bw6[4], bw7[4];
    const unsigned short *Ah, *Al, *wsrc, *wnext;

    // ---- pre-loop prologue: B sets 0..7 of cell 0 into bw0..bw7 ----
    {
        wsrc  = Wcat + (size_t)bj * 65536;            // l=0
        wnext = Wcat + ((size_t)1 * 256 + bj) * 65536;
        BISSUE(bw0, 0, wsrc); BISSUE(bw1, 1, wsrc); BISSUE(bw2, 2, wsrc);
        BISSUE(bw3, 3, wsrc); BISSUE(bw4, 4, wsrc); BISSUE(bw5, 5, wsrc);
        BISSUE(bw6, 6, wsrc); BISSUE(bw7, 7, wsrc);
        __builtin_amdgcn_sched_barrier(0);
    }

#pragma unroll 1
    for (int u = 0; u < NT * NL; ++u) {
        const int t = u >> 2, l = u & 3;
        const int pr = t & 1, pw = pr ^ 1;

        // ---- grid barrier: release-only, tree arrival; inv ONCE per
        //      timestep (window-start; safety proof in header comment) ----
        if (u) {
            if (tid == 0) {
                if ((u & 3) == 0)
                    asm volatile("buffer_inv sc1" ::: "memory");
                unsigned* cg = sync + ((unsigned)bj & 7u) * 16u;   // 64B apart
                unsigned old = __hip_atomic_fetch_add(cg, 1u, __ATOMIC_RELEASE,
                                                      __HIP_MEMORY_SCOPE_AGENT);
                if (old == 32u * (unsigned)u - 1u) {
                    unsigned o2 = __hip_atomic_fetch_add(sync + 128, 1u,
                                                         __ATOMIC_RELEASE,
                                                         __HIP_MEMORY_SCOPE_AGENT);
                    if (o2 == 8u * (unsigned)u - 1u) {
                        __hip_atomic_store(sync + 144, (unsigned)u,
                                           __ATOMIC_RELEASE,
                                           __HIP_MEMORY_SCOPE_AGENT);
                    }
                }
                while (__hip_atomic_load(sync + 144, __ATOMIC_RELAXED,
                                         __HIP_MEMORY_SCOPE_AGENT) < (unsigned)u)
                    __builtin_amdgcn_s_sleep(2);
            }
            asm volatile("s_barrier" ::: "memory");
        }

        // ---- per-cell pointers ----
        {
            const unsigned short *AIh, *AIl;
            if (l == 0) {
                if (t == 0) { AIh = Xhi; AIl = Xlo; }
                else        { AIh = Hhi + HOFF(pr, 3); AIl = Hlo + HOFF(pr, 3); }
            } else          { AIh = Hhi + HOFF(pw, l - 1); AIl = Hlo + HOFF(pw, l - 1); }
            Ah = kh ? (Hhi + HOFF(pr, l)) : AIh;
            Al = kh ? (Hlo + HOFF(pr, l)) : AIl;
            wsrc  = Wcat + ((size_t)l * 256 + bj) * 65536;
            wnext = Wcat + ((size_t)((l + 1) & 3) * 256 + bj) * 65536;
        }

        // ---- A burst: sets 0..3 of this cell (h just became visible) ----
        AISSUE(av0, 0); AISSUE(av1, 1); AISSUE(av2, 2); AISSUE(av3, 3);
        __builtin_amdgcn_sched_barrier(0);

        f32x4 acc0 = {0.f, 0.f, 0.f, 0.f};
        f32x4 acc1 = {0.f, 0.f, 0.f, 0.f};
        f32x4 acc2 = {0.f, 0.f, 0.f, 0.f};

        PHASE( 0, av0, bw0);  PHASE( 1, av1, bw1);
        PHASE( 2, av2, bw2);  PHASE( 3, av3, bw3);
        PHASE( 4, av0, bw4);  PHASE( 5, av1, bw5);
        PHASE( 6, av2, bw6);  PHASE( 7, av3, bw7);
        PHASE( 8, av0, bw0);  PHASE( 9, av1, bw1);
        PHASE(10, av2, bw2);  PHASE(11, av3, bw3);
        PHASE(12, av0, bw4);  PHASE(13, av1, bw5);
        PHASE(14, av2, bw6);  PHASE(15, av3, bw7);

        // ---- scatter partials: tile = kh*4+q; lane holds D[mq*4+r][nl] ----
        {
            f32x4 avv = (acc0 + acc1) + acc2;
            const int mq = L >> 4, nl = L & 15;
            float* gw = &Gs[(kh * 4 + q) * 320 + nl];
#pragma unroll
            for (int r = 0; r < 4; ++r) gw[(mq * 4 + r) * 20] = avv[r];
        }
        asm volatile("s_waitcnt lgkmcnt(0)\n\ts_barrier" ::: "memory");

        // ---- epilogue: wave0, one batch row each, 4 h-dims (R3-verified) ----
        if (tid < 64) {
            const int bl = tid, qq = bl >> 4, ml = bl & 15;
            float4 cv = cLd[l][bl];
            float ca[4] = {cv.x, cv.y, cv.z, cv.w};
            float hv[4];
            ushort4 h_hi, h_lo;
#pragma unroll
            for (int jl = 0; jl < 4; ++jl) {
                const int base0 = (qq * 16 + ml) * 20 + jl * 4;
                float4 g0 = *(const float4*)&Gs[base0];
                float4 g1 = *(const float4*)&Gs[base0 + 1280];
                float4 bb = *(const float4*)&bcs[l * 16 + jl * 4];
                float gi = g0.x + g1.x + bb.x;
                float gf = g0.y + g1.y + bb.y;
                float gg = g0.z + g1.z + bb.z;
                float go = g0.w + g1.w + bb.w;
                float si = 1.f / (1.f + __expf(-gi));
                float sf = 1.f / (1.f + __expf(-gf));
                float so = 1.f / (1.f + __expf(-go));
                float tg = 1.f - 2.f / (__expf(2.f * gg) + 1.f);
                float cn = sf * ca[jl] + si * tg;
                ca[jl] = cn;
                float tc = 1.f - 2.f / (__expf(2.f * cn) + 1.f);
                hv[jl] = so * tc;
                unsigned short hh, hl; split_bf16(hv[jl], hh, hl);
                ((unsigned short*)&h_hi)[jl] = hh;
                ((unsigned short*)&h_lo)[jl] = hl;
            }
            cLd[l][bl] = make_float4(ca[0], ca[1], ca[2], ca[3]);
            size_t hidx = aswz(bl, bj * 4);
            union { ushort4 v; unsigned long long u; } ch, cl2;
            ch.v = h_hi; cl2.v = h_lo;
            __hip_atomic_store((unsigned long long*)(Hhi + HOFF(pw, l) + hidx), ch.u,
                               __ATOMIC_RELAXED, __HIP_MEMORY_SCOPE_AGENT);
            __hip_atomic_store((unsigned long long*)(Hlo + HOFF(pw, l) + hidx), cl2.u,
                               __ATOMIC_RELAXED, __HIP_MEMORY_SCOPE_AGENT);
            if (l == 3) {
                // write-through (agent atomic) so a buffer_inv can never drop
                // a dirty out line from L2.
                union { float4 f; unsigned long long uu[2]; } ov;
                ov.f = make_float4(hv[0], hv[1], hv[2], hv[3]);
                unsigned long long* op = (unsigned long long*)
                    &out[(size_t)bl * (NT * NH) + (size_t)t * NH + bj * 4];
                __hip_atomic_store(op,     ov.uu[0], __ATOMIC_RELAXED,
                                   __HIP_MEMORY_SCOPE_AGENT);
                __hip_atomic_store(op + 1, ov.uu[1], __ATOMIC_RELAXED,
                                   __HIP_MEMORY_SCOPE_AGENT);
            }
        }
    }
}

// ---------------------------------------------------------------------------
extern "C" void kernel_launch(void* const* d_in, const int* in_sizes, int n_in,
                              void* d_out, int out_size, void* d_ws, size_t ws_size,
                              hipStream_t stream)
{
    const float* x   = (const float*)d_in[0];
    const float* h0  = (const float*)d_in[1];
    const float* c0  = (const float*)d_in[2];
    const float* Wih = (const float*)d_in[3];
    const float* Whh = (const float*)d_in[4];
    const float* bih = (const float*)d_in[5];
    const float* bhh = (const float*)d_in[6];
    float* out = (float*)d_out;

    char* ws = (char*)d_ws;
    size_t off = 0;
    auto alloc = [&](size_t bytes) -> char* {
        char* p = ws + off; off += (bytes + 255) & ~(size_t)255; return p;
    };
    unsigned short* Wcat = (unsigned short*)alloc((size_t)4 * 256 * 65536 * 2);  // 128 MiB
    unsigned short* Xhi  = (unsigned short*)alloc(65536 * 2);
    unsigned short* Xlo  = (unsigned short*)alloc(65536 * 2);
    unsigned short* Hhi  = (unsigned short*)alloc((size_t)2 * 4 * 65536 * 2);
    unsigned short* Hlo  = (unsigned short*)alloc((size_t)2 * 4 * 65536 * 2);
    unsigned*       sync = (unsigned*)alloc(1024);

    hipMemsetAsync(sync, 0, 1024, stream);
    prep_w<<<16384, 256, 0, stream>>>(Wih, Whh, Wcat);
    prep_state<<<1280, 256, 0, stream>>>(x, h0, Xhi, Xlo, Hhi, Hlo);

    void* kargs[] = { (void*)&Wcat, (void*)&Xhi, (void*)&Xlo, (void*)&Hhi, (void*)&Hlo,
                      (void*)&c0, (void*)&bih, (void*)&bhh, (void*)&out, (void*)&sync };
    hipLaunchCooperativeKernel((void*)lstm_fused, dim3(256), dim3(512), kargs, 0, stream);

    (void)in_sizes; (void)n_in; (void)out_size; (void)ws_size;
}